// Round 6
// baseline (363.993 us; speedup 1.0000x reference)
//
#include <hip/hip_runtime.h>
#include <math.h>

// Problem constants
#define BATCH   8
#define SEQ     512
#define HID     2048
#define NH      32
#define NKV     8
#define HD      64

typedef unsigned short u16;
typedef __attribute__((ext_vector_type(8))) short  s16x8;
typedef __attribute__((ext_vector_type(4))) float  f32x4;

// ---- bf16 helpers (RNE, bit-level) ----------------------------------------
__device__ __forceinline__ u16 f2bf(float f) {
  unsigned u = __builtin_bit_cast(unsigned, f);
  u += 0x7fffu + ((u >> 16) & 1u);
  return (u16)(u >> 16);
}
__device__ __forceinline__ float bf2f(u16 h) {
  unsigned u = ((unsigned)h) << 16;
  return __builtin_bit_cast(float, u);
}
__device__ __forceinline__ void split_bf16(float v, u16& h, u16& l) {
  h = f2bf(v);
  l = f2bf(v - bf2f(h));
}

// async global->LDS, 16B per lane
#define GL16(gp, lp) __builtin_amdgcn_global_load_lds(                         \
    (const __attribute__((address_space(1))) void*)(gp),                       \
    (__attribute__((address_space(3))) void*)(lp), 16, 0, 0)

#define MFMA16(a, b, c) __builtin_amdgcn_mfma_f32_16x16x32_bf16((a), (b), (c), 0, 0, 0)

// ---------------------------------------------------------------------------
// Pre-pass: fp32 -> single bf16 plane (elementwise).
// ---------------------------------------------------------------------------
__global__ __launch_bounds__(256) void cast_x(const float* __restrict__ src,
                                              u16* __restrict__ dst)
{
  int i = blockIdx.x * 256 + threadIdx.x;
  float4 v = ((const float4*)src)[i];
  ushort4 hh;
  hh.x = f2bf(v.x); hh.y = f2bf(v.y); hh.z = f2bf(v.z); hh.w = f2bf(v.w);
  ((ushort4*)dst)[i] = hh;
}

// ---------------------------------------------------------------------------
// Pre-pass: transpose + cast W [2048 x N] -> BT [nofs+n][2048] bf16 single.
// ---------------------------------------------------------------------------
__global__ __launch_bounds__(256) void tcast_w(const float* __restrict__ W, int N,
                                               u16* __restrict__ BT, int nofs)
{
  __shared__ float t[64][68];
  const int nt = blockIdx.x * 64, kt = blockIdx.y * 64;
  const int tid = threadIdx.x;
  const int c4 = (tid & 15) * 4, r0 = tid >> 4;
  #pragma unroll
  for (int i = 0; i < 4; i++) {
    int r = r0 + i * 16;
    float4 v = *(const float4*)(&W[(size_t)(kt + r) * N + nt + c4]);
    t[c4 + 0][r] = v.x; t[c4 + 1][r] = v.y; t[c4 + 2][r] = v.z; t[c4 + 3][r] = v.w;
  }
  __syncthreads();
  #pragma unroll
  for (int i = 0; i < 4; i++) {
    int rr = r0 + i * 16;
    float4 v = *(const float4*)(&t[rr][c4]);
    ushort4 hh;
    hh.x = f2bf(v.x); hh.y = f2bf(v.y); hh.z = f2bf(v.z); hh.w = f2bf(v.w);
    *(ushort4*)(&BT[(size_t)(nofs + nt + rr) * 2048 + kt + c4]) = hh;
  }
}

// ---------------------------------------------------------------------------
// MFMA GEMM main loop (128x128 tile, BK=32, 4 waves), single bf16 x bf16.
// A [M][2048] row-major; B [N][2048] row-major (= W^T).
// ---------------------------------------------------------------------------
__device__ __forceinline__ void gemm_main1(
    const u16* __restrict__ A, const u16* __restrict__ B,
    int mtile, int ntile,
    u16* sA, u16* sB,
    f32x4 acc[4][4])
{
  const int tid  = threadIdx.x;
  const int lane = tid & 63;
  const int w    = tid >> 6;
  const int wr = (w >> 1) * 64, wc = (w & 1) * 64;
  const int fr = lane & 15, fk = (lane >> 4) * 8;

  const int r0 = tid >> 2, c0 = (tid & 3) * 8;
  const size_t a0 = (size_t)(mtile + r0) * 2048 + c0;
  const size_t a1 = (size_t)(mtile + r0 + 64) * 2048 + c0;
  const size_t b0 = (size_t)(ntile + r0) * 2048 + c0;
  const size_t b1 = (size_t)(ntile + r0 + 64) * 2048 + c0;
  const int d0 = tid * 8, d1 = tid * 8 + 2048;

  for (int kt = 0; kt < 2048; kt += 32) {
    GL16(A + a0 + kt, sA + d0);
    GL16(A + a1 + kt, sA + d1);
    GL16(B + b0 + kt, sB + d0);
    GL16(B + b1 + kt, sB + d1);
    __syncthreads();

    s16x8 bf[4];
    #pragma unroll
    for (int ni = 0; ni < 4; ni++)
      bf[ni] = *(const s16x8*)(&sB[(wc + ni * 16 + fr) * 32 + fk]);
    #pragma unroll
    for (int mi = 0; mi < 4; mi++) {
      s16x8 a = *(const s16x8*)(&sA[(wr + mi * 16 + fr) * 32 + fk]);
      #pragma unroll
      for (int ni = 0; ni < 4; ni++)
        acc[mi][ni] = MFMA16(a, bf[ni], acc[mi][ni]);
    }
    __syncthreads();
  }
}

// ---------------------------------------------------------------------------
// Fused QKV projection + in-register RoPE + plane emission.
// N-tiles [0,2048): Q -> roped+scaled bf16 hi/lo planes [m][2048]
// N-tiles [2048,2560): K -> roped fp32 k-cache + single bf16 plane [bh][s][d]
// N-tiles [2560,3072): V -> fp32 v-cache + bf16 transposed plane [bh][d][s]
// ---------------------------------------------------------------------------
#define L2_10K 13.28771238f   // log2(10000)

__global__ __launch_bounds__(256, 2) void gemm_qkv(
    const u16* __restrict__ A, const u16* __restrict__ B,
    u16* __restrict__ Qh, u16* __restrict__ Ql,
    float* __restrict__ kout, float* __restrict__ vout,
    u16* __restrict__ Kp, u16* __restrict__ Vt)
{
  __shared__ __align__(16) u16 sA[128 * 32], sB[128 * 32];
  const int ntile = blockIdx.x * 128, mtile = blockIdx.y * 128;
  f32x4 acc[4][4] = {};
  gemm_main1(A, B, mtile, ntile, sA, sB, acc);

  const int lane = threadIdx.x & 63, w = threadIdx.x >> 6;
  const int wr = (w >> 1) * 64, wc = (w & 1) * 64;
  const int orow = (lane >> 4) * 4, ocol = lane & 15;

  if (ntile < 2048) {
    float inv[2];
    #pragma unroll
    for (int nj = 0; nj < 2; nj++)
      inv[nj] = exp2f((float)(nj * 16 + ocol) * (-L2_10K / 32.0f));
    #pragma unroll
    for (int mi = 0; mi < 4; mi++)
      #pragma unroll
      for (int r = 0; r < 4; r++) {
        int m = mtile + wr + mi * 16 + orow + r;
        int s = m & 511;
        #pragma unroll
        for (int nj = 0; nj < 2; nj++) {
          float th = (float)s * inv[nj];
          float sn, cs; sincosf(th, &sn, &cs);
          float a0 = acc[mi][nj][r]     * 0.125f;   // scale folded into Q
          float a1 = acc[mi][nj + 2][r] * 0.125f;
          float q0 = a0 * cs - a1 * sn;
          float q1 = a1 * cs + a0 * sn;
          size_t o0 = (size_t)m * 2048 + ntile + wc + nj * 16 + ocol;
          u16 hh, ll;
          split_bf16(q0, hh, ll); Qh[o0] = hh;      Ql[o0] = ll;
          split_bf16(q1, hh, ll); Qh[o0 + 32] = hh; Ql[o0 + 32] = ll;
        }
      }
  } else if (ntile < 2560) {
    float inv[2];
    #pragma unroll
    for (int nj = 0; nj < 2; nj++)
      inv[nj] = exp2f((float)(nj * 16 + ocol) * (-L2_10K / 32.0f));
    #pragma unroll
    for (int mi = 0; mi < 4; mi++)
      #pragma unroll
      for (int r = 0; r < 4; r++) {
        int m = mtile + wr + mi * 16 + orow + r;
        int bb = m >> 9, s = m & 511;
        #pragma unroll
        for (int nj = 0; nj < 2; nj++) {
          int np = ntile + wc + nj * 16 + ocol - 2048;
          int hk = np >> 6, d = np & 63;            // d in [0,32)
          float th = (float)s * inv[nj];
          float sn, cs; sincosf(th, &sn, &cs);
          float a0 = acc[mi][nj][r];
          float a1 = acc[mi][nj + 2][r];
          float k0 = a0 * cs - a1 * sn;
          float k1 = a1 * cs + a0 * sn;
          size_t o = ((size_t)(bb * 8 + hk) * 512 + s) * 64 + d;
          kout[o] = k0;           kout[o + 32] = k1;
          Kp[o]   = f2bf(k0);     Kp[o + 32]   = f2bf(k1);
        }
      }
  } else {
    #pragma unroll
    for (int mi = 0; mi < 4; mi++)
      #pragma unroll
      for (int ni = 0; ni < 4; ni++) {
        int np = ntile + wc + ni * 16 + ocol - 2560;
        int hk = np >> 6, d = np & 63;
        int m0 = mtile + wr + mi * 16 + orow;
        int bb = m0 >> 9, s0 = m0 & 511;            // multiple of 4
        ushort4 pk;
        #pragma unroll
        for (int r = 0; r < 4; r++) {
          float v = acc[mi][ni][r];
          vout[((size_t)(bb * 8 + hk) * 512 + s0 + r) * 64 + d] = v;
          ((u16*)&pk)[r] = f2bf(v);
        }
        *(ushort4*)(&Vt[((size_t)(bb * 8 + hk) * 64 + d) * 512 + s0]) = pk;
      }
  }
}

// ---------------------------------------------------------------------------
// Output projection: out = Ao[4096,2048] @ Wo, single bf16 x single bf16.
// ---------------------------------------------------------------------------
__global__ __launch_bounds__(256, 2) void gemm_out(
    const u16* __restrict__ A, const u16* __restrict__ B,
    float* __restrict__ Cout)
{
  __shared__ __align__(16) u16 sA[128 * 32], sB[128 * 32];
  const int ntile = blockIdx.x * 128, mtile = blockIdx.y * 128;
  f32x4 acc[4][4] = {};
  gemm_main1(A, B, mtile, ntile, sA, sB, acc);

  const int lane = threadIdx.x & 63, w = threadIdx.x >> 6;
  const int wr = (w >> 1) * 64, wc = (w & 1) * 64;
  const int orow = (lane >> 4) * 4, ocol = lane & 15;
  #pragma unroll
  for (int mi = 0; mi < 4; mi++)
    #pragma unroll
    for (int r = 0; r < 4; r++) {
      int m = mtile + wr + mi * 16 + orow + r;
      #pragma unroll
      for (int ni = 0; ni < 4; ni++)
        Cout[(size_t)m * 2048 + ntile + wc + ni * 16 + ocol] = acc[mi][ni][r];
    }
}

// ---------------------------------------------------------------------------
// MFMA flash attention, no K/V LDS staging (K/V per (b,hk) is ~130 KB and
// reused by 4 heads -> L2-resident; staging it was pure overhead, m169).
// MFMA fragments read DIRECTLY from global (16B/lane aligned). No barriers:
// waves fully independent; only per-wave P strip lives in LDS (8 KB total).
// QK^T = 2-term (Qh+Ql) x K-bf16; PV = bf16.
// ---------------------------------------------------------------------------
__global__ __launch_bounds__(256, 4)
void attn(const u16* __restrict__ Qh, const u16* __restrict__ Ql,
          const u16* __restrict__ Kp, const u16* __restrict__ Vt,
          u16* __restrict__ Ao)
{
  __shared__ __align__(16) u16 sP[4][1024];   // 2 KB per wave, XOR-swizzled

  const int qt = blockIdx.x, h = blockIdx.y, bb = blockIdx.z;
  const int hk = h >> 2, bh = bb * 8 + hk;
  const int tid = threadIdx.x, lane = tid & 63, w = tid >> 6;
  const int fr = lane & 15, fg = lane >> 4;

  // Q fragments, hoisted (rows w*16+fr), hi/lo planes
  const int qrow = bb * 512 + qt * 64 + w * 16 + fr;
  const size_t qoff = (size_t)qrow * 2048 + h * 64 + fg * 8;
  const s16x8 qh0 = *(const s16x8*)(Qh + qoff);
  const s16x8 qh1 = *(const s16x8*)(Qh + qoff + 32);
  const s16x8 ql0 = *(const s16x8*)(Ql + qoff);
  const s16x8 ql1 = *(const s16x8*)(Ql + qoff + 32);

  f32x4 oacc[4] = {};
  float m_r[4] = {-1e30f, -1e30f, -1e30f, -1e30f};
  float l_r[4] = {};

  const size_t kbase = (size_t)bh * 512 * 64;   // Kp [bh][s][d]
  const size_t vbase = (size_t)bh * 64 * 512;   // Vt [bh][d][s]

  for (int j = 0; j <= qt; j++) {
    const u16* kb = Kp + kbase + (size_t)j * 64 * 64;
    const u16* vb = Vt + vbase + j * 64;

    // ---- S = (Q*scale) K^T, fragments straight from global ----
    f32x4 sacc[4] = {};
    #pragma unroll
    for (int ni = 0; ni < 4; ni++) {
      #pragma unroll
      for (int ks = 0; ks < 2; ks++) {
        s16x8 k = *(const s16x8*)(kb + (ni * 16 + fr) * 64 + ks * 32 + fg * 8);
        f32x4 c = sacc[ni];
        c = MFMA16(ks ? qh1 : qh0, k, c);
        c = MFMA16(ks ? ql1 : ql0, k, c);
        sacc[ni] = c;
      }
    }

    // ---- causal mask + online softmax (rows = fg*4+r, cols over fr,ni) ----
    const int rowg0 = qt * 64 + w * 16 + fg * 4;
    #pragma unroll
    for (int r = 0; r < 4; r++) {
      float mx = -1e30f;
      #pragma unroll
      for (int ni = 0; ni < 4; ni++) {
        int col = j * 64 + ni * 16 + fr;
        float v = (col <= rowg0 + r) ? sacc[ni][r] : -1e30f;
        sacc[ni][r] = v;
        mx = fmaxf(mx, v);
      }
      mx = fmaxf(mx, __shfl_xor(mx, 1));
      mx = fmaxf(mx, __shfl_xor(mx, 2));
      mx = fmaxf(mx, __shfl_xor(mx, 4));
      mx = fmaxf(mx, __shfl_xor(mx, 8));
      float mnew = fmaxf(m_r[r], mx);
      float sc = __expf(m_r[r] - mnew);
      m_r[r] = mnew;
      float ls = 0.0f;
      #pragma unroll
      for (int ni = 0; ni < 4; ni++) {
        float p = __expf(sacc[ni][r] - mnew);
        sacc[ni][r] = p;
        ls += p;
      }
      ls += __shfl_xor(ls, 1);
      ls += __shfl_xor(ls, 2);
      ls += __shfl_xor(ls, 4);
      ls += __shfl_xor(ls, 8);
      l_r[r] = l_r[r] * sc + ls;
      #pragma unroll
      for (int nd = 0; nd < 4; nd++) oacc[nd][r] *= sc;
    }

    // ---- P -> per-wave LDS strip (bf16, swizzled; same-wave, no barrier) --
    u16* pbuf = sP[w];
    #pragma unroll
    for (int ni = 0; ni < 4; ni++)
      #pragma unroll
      for (int r = 0; r < 4; r++) {
        int prow = fg * 4 + r, pcol = ni * 16 + fr;
        int byte = prow * 128 + ((pcol * 2) ^ ((prow & 7) << 4));
        *(u16*)((char*)pbuf + byte) = f2bf(sacc[ni][r]);
      }

    // ---- O += P V (V fragments straight from global) ----
    #pragma unroll
    for (int ks = 0; ks < 2; ks++) {
      int pbyte = fr * 128 + ((fg * 16 + ks * 64) ^ ((fr & 7) << 4));
      s16x8 pa = *(const s16x8*)((const char*)pbuf + pbyte);
      #pragma unroll
      for (int nd = 0; nd < 4; nd++) {
        s16x8 vv = *(const s16x8*)(vb + (size_t)(nd * 16 + fr) * 512 + ks * 32 + fg * 8);
        oacc[nd] = MFMA16(pa, vv, oacc[nd]);
      }
    }
  }

  // ---- epilogue: normalize, emit single bf16 plane [m][2048] ----
  const size_t obase = (size_t)(bb * 512 + qt * 64 + w * 16 + fg * 4) * 2048 + h * 64;
  #pragma unroll
  for (int r = 0; r < 4; r++) {
    float inv = 1.0f / l_r[r];
    #pragma unroll
    for (int nd = 0; nd < 4; nd++)
      Ao[obase + (size_t)r * 2048 + nd * 16 + fr] = f2bf(oacc[nd][r] * inv);
  }
}

// ---------------------------------------------------------------------------
extern "C" void kernel_launch(void* const* d_in, const int* in_sizes, int n_in,
                              void* d_out, int out_size, void* d_ws, size_t ws_size,
                              hipStream_t stream)
{
  const float* x  = (const float*)d_in[0];
  const float* Wq = (const float*)d_in[1];
  const float* Wk = (const float*)d_in[2];
  const float* Wv = (const float*)d_in[3];
  const float* Wo = (const float*)d_in[4];

  float* out  = (float*)d_out;                 // [B,S,2048]
  float* kout = out + 8388608;                 // k cache [B,8,S,64]
  float* vout = out + 10485760;                // v cache [B,8,S,64]

  // Workspace layout (68 MiB):
  //  [0,16M)     xbf single plane -> Ao single plane (alias)
  //  [16M,28M)   Wqkv single plane [3072][2048]; Wo plane aliases front 8M
  //  [28M,44M)   Qh roped+scaled bf16 plane
  //  [44M,60M)   Ql plane
  //  [60M,64M)   Kp roped single bf16 plane [bh][s][d]
  //  [64M,68M)   Vt transposed bf16 plane [bh][d][s]
  uint8_t* wsb = (uint8_t*)d_ws;
  u16* xbf = (u16*)(wsb + 0);
  u16* Ao  = xbf;                              // alias: x dead after gemm_qkv
  u16* Wqp = (u16*)(wsb + 16777216);           // [3072][2048]
  u16* Wop = (u16*)(wsb + 16777216);           // alias: Wqkv dead after gemm_qkv
  u16* Qhp = (u16*)(wsb + 29360128);
  u16* Qlp = (u16*)(wsb + 46137344);
  u16* Kpp = (u16*)(wsb + 62914560);
  u16* Vtp = (u16*)(wsb + 67108864);

  cast_x<<<8192, 256, 0, stream>>>(x, xbf);
  tcast_w<<<dim3(32, 32), 256, 0, stream>>>(Wq, 2048, Wqp, 0);
  tcast_w<<<dim3(8, 32), 256, 0, stream>>>(Wk, 512, Wqp, 2048);
  tcast_w<<<dim3(8, 32), 256, 0, stream>>>(Wv, 512, Wqp, 2560);
  gemm_qkv<<<dim3(24, 32), 256, 0, stream>>>(xbf, Wqp,
                                             Qhp, Qlp, kout, vout, Kpp, Vtp);
  tcast_w<<<dim3(32, 32), 256, 0, stream>>>(Wo, 2048, Wop, 0);
  attn<<<dim3(8, 32, 8), 256, 0, stream>>>(Qhp, Qlp, Kpp, Vtp, Ao);
  gemm_out<<<dim3(16, 32), 256, 0, stream>>>(Ao, Wop, out);
}